// Round 5
// baseline (49.595 us; speedup 1.0000x reference)
//
#include <hip/hip_runtime.h>

#define U 128
#define NSEG 32
#define NPATH 512
#define ROW (NSEG * U)   // 4096 floats per batch row
#define NW 8             // waves per tp block (512 threads)

// Path metadata, grouped (order-preserving) by pout.
struct Meta { unsigned pp; float c; };   // pp = p0 | (p1 << 16)
struct WS {
    Meta meta[NPATH];        // 4096 B
    int  segstart[NSEG + 1]; // CSR boundaries into meta[]
    int  wsplit[NW + 1];     // segment-boundary split per wave
};

// One block, 512 threads: thread k owns path k. Deterministic parallel
// counting-sort by pout (original-k order preserved within each segment).
__global__ __launch_bounds__(512) void build_csr(const float* __restrict__ coeffs,
                                                 const int* __restrict__ p0,
                                                 const int* __restrict__ p1,
                                                 const int* __restrict__ pout,
                                                 WS* __restrict__ ws) {
    __shared__ int wcnt[NPATH / 64][NSEG];   // per-wave per-segment counts
    __shared__ int wpre[NPATH / 64][NSEG];   // prefix over earlier waves
    __shared__ int sseg[NSEG + 1];
    __shared__ int stot[NSEG];

    const int k    = threadIdx.x;
    const int lane = k & 63;
    const int wave = k >> 6;

    const int   po = pout[k];
    const int   a0 = p0[k];
    const int   a1 = p1[k];
    const float c  = coeffs[k];

    // rank within wave + per-wave counts, via 32 ballots
    const unsigned long long lt = (1ull << lane) - 1ull;
    int rank = 0;
    #pragma unroll
    for (int s = 0; s < NSEG; ++s) {
        unsigned long long m = __ballot(po == s);
        if (po == s)  rank = (int)__popcll(m & lt);
        if (lane == s) wcnt[wave][s] = (int)__popcll(m);
    }
    __syncthreads();

    // per-segment: prefix over waves + totals (threads 0..31)
    if (k < NSEG) {
        int tot = 0;
        #pragma unroll
        for (int w = 0; w < NPATH / 64; ++w) { wpre[w][k] = tot; tot += wcnt[w][k]; }
        stot[k] = tot;
    }
    __syncthreads();

    // exclusive scan of totals over segments (wave 0)
    if (k < 64) {
        int v = (k < NSEG) ? stot[k] : 0;
        int inc = v;
        #pragma unroll
        for (int d = 1; d < 64; d <<= 1) {
            int t = __shfl_up(inc, d, 64);
            if (k >= d) inc += t;
        }
        int excl = inc - v;
        if (k < NSEG) sseg[k] = excl;
        if (k == NSEG - 1) sseg[NSEG] = excl + v;
    }
    __syncthreads();

    // scatter (deterministic position)
    {
        Meta m;
        m.pp = (unsigned)a0 | ((unsigned)a1 << 16);
        m.c  = c;
        ws->meta[sseg[po] + wpre[wave][po] + rank] = m;
    }
    if (k <= NSEG) ws->segstart[k] = sseg[k];

    // balanced NW-way split boundaries (wave 0); argmin |segstart - target|
    if (k < 64) {
        #pragma unroll
        for (int w = 1; w < NW; ++w) {
            const int target = (NPATH * w) / NW;
            int key;
            if (k <= NSEG) {
                int d = sseg[k] - target; if (d < 0) d = -d;
                key = (d << 6) | k;
            } else key = 0x7fffffff;
            #pragma unroll
            for (int m = 32; m >= 1; m >>= 1) {
                int o = __shfl_xor(key, m, 64);
                key = (o < key) ? o : key;
            }
            if (k == 0) ws->wsplit[w] = key & 63;
        }
        if (k == 0) { ws->wsplit[0] = 0; ws->wsplit[NW] = NSEG; }
    }
}

// One block (512 threads, 8 waves) per batch row. x0/x1 rows in LDS (32 KiB);
// ALL metadata (meta, segstart, wsplit) read from global with wave-uniform
// indices -> scalar loads on the SALU/sL1 path, zero LDS-pipe cost. Full-wave
// float2 per lane per path: 2x ds_read_b64 / path, 1 v_add per address.
__global__ __launch_bounds__(512) void tp_kernel(const float* __restrict__ x0,
                                                 const float* __restrict__ x1,
                                                 const WS* __restrict__ ws,
                                                 float* __restrict__ out) {
    __shared__ float lds0[ROW];
    __shared__ float lds1[ROW];

    const int b   = blockIdx.x;
    const int tid = threadIdx.x;

    // stage rows (coalesced float4)
    const float4* g0 = reinterpret_cast<const float4*>(x0 + (size_t)b * ROW);
    const float4* g1 = reinterpret_cast<const float4*>(x1 + (size_t)b * ROW);
    float4* s0v = reinterpret_cast<float4*>(lds0);
    float4* s1v = reinterpret_cast<float4*>(lds1);
    #pragma unroll
    for (int j = 0; j < (ROW / 4) / 512; ++j) {   // 2 iters each
        s0v[tid + j * 512] = g0[tid + j * 512];
        s1v[tid + j * 512] = g1[tid + j * 512];
    }
    __syncthreads();

    const int wave = tid >> 6;
    const int lane = tid & 63;

    const Meta* __restrict__ gm   = ws->meta;      // uniform-index -> s_load
    const int*  __restrict__ gseg = ws->segstart;
    const int*  __restrict__ gspl = ws->wsplit;

    const int sBeg = gspl[wave];       // wave-uniform
    const int sEnd = gspl[wave + 1];

    const float2* s0p = reinterpret_cast<const float2*>(lds0);
    const float2* s1p = reinterpret_cast<const float2*>(lds1);
    float* outrow = out + (size_t)b * ROW;

    for (int s = sBeg; s < sEnd; ++s) {
        const int jb = gseg[s];
        const int je = gseg[s + 1];
        float2 aA = make_float2(0.f, 0.f);
        float2 aB = make_float2(0.f, 0.f);
        int j = jb;
        for (; j + 3 < je; j += 4) {   // 4 paths in flight
            const Meta m0 = gm[j];
            const Meta m1 = gm[j + 1];
            const Meta m2 = gm[j + 2];
            const Meta m3 = gm[j + 3];
            const float2 u0 = s0p[(m0.pp & 0xffffu) * (U / 2) + lane];
            const float2 w0 = s1p[(m0.pp >> 16)     * (U / 2) + lane];
            const float2 u1 = s0p[(m1.pp & 0xffffu) * (U / 2) + lane];
            const float2 w1 = s1p[(m1.pp >> 16)     * (U / 2) + lane];
            const float2 u2 = s0p[(m2.pp & 0xffffu) * (U / 2) + lane];
            const float2 w2 = s1p[(m2.pp >> 16)     * (U / 2) + lane];
            const float2 u3 = s0p[(m3.pp & 0xffffu) * (U / 2) + lane];
            const float2 w3 = s1p[(m3.pp >> 16)     * (U / 2) + lane];
            aA.x += m0.c * u0.x * w0.x;  aA.y += m0.c * u0.y * w0.y;
            aB.x += m1.c * u1.x * w1.x;  aB.y += m1.c * u1.y * w1.y;
            aA.x += m2.c * u2.x * w2.x;  aA.y += m2.c * u2.y * w2.y;
            aB.x += m3.c * u3.x * w3.x;  aB.y += m3.c * u3.y * w3.y;
        }
        for (; j < je; ++j) {
            const Meta m = gm[j];
            const float2 u = s0p[(m.pp & 0xffffu) * (U / 2) + lane];
            const float2 w = s1p[(m.pp >> 16)     * (U / 2) + lane];
            aA.x += m.c * u.x * w.x;
            aA.y += m.c * u.y * w.y;
        }
        float2 o;
        o.x = aA.x + aB.x;
        o.y = aA.y + aB.y;
        reinterpret_cast<float2*>(outrow)[s * (U / 2) + lane] = o;
    }
}

extern "C" void kernel_launch(void* const* d_in, const int* in_sizes, int n_in,
                              void* d_out, int out_size, void* d_ws, size_t ws_size,
                              hipStream_t stream) {
    const float* x0     = (const float*)d_in[0];
    const float* x1     = (const float*)d_in[1];
    const float* coeffs = (const float*)d_in[2];
    const int*   p0     = (const int*)d_in[3];
    const int*   p1     = (const int*)d_in[4];
    const int*   pout   = (const int*)d_in[5];
    float* out = (float*)d_out;
    WS* ws = (WS*)d_ws;

    build_csr<<<1, 512, 0, stream>>>(coeffs, p0, p1, pout, ws);
    tp_kernel<<<2048, 512, 0, stream>>>(x0, x1, ws, out);
}

// Round 6
// 35.935 us; speedup vs baseline: 1.3801x; 1.3801x over previous
//
#include <hip/hip_runtime.h>

#define U 128
#define NSEG 32
#define NPATH 512
#define ROW (NSEG * U)   // 4096 floats per batch row
#define NW 8             // waves per tp block (512 threads)

// Path metadata, grouped (order-preserving) by pout.
struct Meta { unsigned pp; float c; };   // pp = p0 | (p1 << 16)
struct WS {
    Meta meta[NPATH];        // 4096 B
    int  segstart[NSEG + 1]; // CSR boundaries into meta[]
    int  wsplit[NW + 1];     // segment-boundary split per wave
};

// One block, 512 threads: thread k owns path k. Deterministic parallel
// counting-sort by pout (original-k order preserved within each segment).
__global__ __launch_bounds__(512) void build_csr(const float* __restrict__ coeffs,
                                                 const int* __restrict__ p0,
                                                 const int* __restrict__ p1,
                                                 const int* __restrict__ pout,
                                                 WS* __restrict__ ws) {
    __shared__ int wcnt[NPATH / 64][NSEG];   // per-wave per-segment counts
    __shared__ int wpre[NPATH / 64][NSEG];   // prefix over earlier waves
    __shared__ int sseg[NSEG + 1];
    __shared__ int stot[NSEG];

    const int k    = threadIdx.x;
    const int lane = k & 63;
    const int wave = k >> 6;

    const int   po = pout[k];
    const int   a0 = p0[k];
    const int   a1 = p1[k];
    const float c  = coeffs[k];

    // rank within wave + per-wave counts, via 32 ballots
    const unsigned long long lt = (1ull << lane) - 1ull;
    int rank = 0;
    #pragma unroll
    for (int s = 0; s < NSEG; ++s) {
        unsigned long long m = __ballot(po == s);
        if (po == s)  rank = (int)__popcll(m & lt);
        if (lane == s) wcnt[wave][s] = (int)__popcll(m);
    }
    __syncthreads();

    // per-segment: prefix over waves + totals (threads 0..31)
    if (k < NSEG) {
        int tot = 0;
        #pragma unroll
        for (int w = 0; w < NPATH / 64; ++w) { wpre[w][k] = tot; tot += wcnt[w][k]; }
        stot[k] = tot;
    }
    __syncthreads();

    // exclusive scan of totals over segments (wave 0)
    if (k < 64) {
        int v = (k < NSEG) ? stot[k] : 0;
        int inc = v;
        #pragma unroll
        for (int d = 1; d < 64; d <<= 1) {
            int t = __shfl_up(inc, d, 64);
            if (k >= d) inc += t;
        }
        int excl = inc - v;
        if (k < NSEG) sseg[k] = excl;
        if (k == NSEG - 1) sseg[NSEG] = excl + v;
    }
    __syncthreads();

    // scatter (deterministic position)
    {
        Meta m;
        m.pp = (unsigned)a0 | ((unsigned)a1 << 16);
        m.c  = c;
        ws->meta[sseg[po] + wpre[wave][po] + rank] = m;
    }
    if (k <= NSEG) ws->segstart[k] = sseg[k];

    // balanced NW-way split boundaries (wave 0); argmin |segstart - target|
    if (k < 64) {
        #pragma unroll
        for (int w = 1; w < NW; ++w) {
            const int target = (NPATH * w) / NW;
            int key;
            if (k <= NSEG) {
                int d = sseg[k] - target; if (d < 0) d = -d;
                key = (d << 6) | k;
            } else key = 0x7fffffff;
            #pragma unroll
            for (int m = 32; m >= 1; m >>= 1) {
                int o = __shfl_xor(key, m, 64);
                key = (o < key) ? o : key;
            }
            if (k == 0) ws->wsplit[w] = key & 63;
        }
        if (k == 0) { ws->wsplit[0] = 0; ws->wsplit[NW] = NSEG; }
    }
}

// One block (512 threads, 8 waves) per batch row. Pair scheme: lanes 0-31
// process path j, lanes 32-63 path j+1 (same segment), each lane a float4
// (ds_read_b128). Metadata in LDS; NEXT group's metas are loaded before the
// CURRENT group's data reads (in-order lgkmcnt completion -> meta->address
// bubble is hidden under the previous group's data wait).
__global__ __launch_bounds__(512, 8) void tp_kernel(const float* __restrict__ x0,
                                                    const float* __restrict__ x1,
                                                    const WS* __restrict__ ws,
                                                    float* __restrict__ out) {
    __shared__ float lds0[ROW];
    __shared__ float lds1[ROW];
    __shared__ Meta  smeta[NPATH];
    __shared__ int   sseg[NSEG + 1];
    __shared__ int   ssplit[NW + 1];

    const int b   = blockIdx.x;
    const int tid = threadIdx.x;

    // stage rows (coalesced float4)
    const float4* g0 = reinterpret_cast<const float4*>(x0 + (size_t)b * ROW);
    const float4* g1 = reinterpret_cast<const float4*>(x1 + (size_t)b * ROW);
    float4* s0v = reinterpret_cast<float4*>(lds0);
    float4* s1v = reinterpret_cast<float4*>(lds1);
    #pragma unroll
    for (int j = 0; j < (ROW / 4) / 512; ++j) {   // 2 iters each
        s0v[tid + j * 512] = g0[tid + j * 512];
        s1v[tid + j * 512] = g1[tid + j * 512];
    }
    if (tid < NPATH / 2)   // 4 KiB of metadata as float4
        reinterpret_cast<float4*>(smeta)[tid] =
            reinterpret_cast<const float4*>(ws->meta)[tid];
    if (tid < NSEG + 1) sseg[tid] = ws->segstart[tid];
    if (tid < NW + 1)   ssplit[tid] = ws->wsplit[tid];
    __syncthreads();

    const int wave = tid >> 6;
    const int lane = tid & 63;
    const int half = lane >> 5;   // 0: low 32 lanes, 1: high 32 lanes
    const int sub  = lane & 31;   // float4 slot within a segment

    const int sBeg = __builtin_amdgcn_readfirstlane(ssplit[wave]);
    const int sEnd = __builtin_amdgcn_readfirstlane(ssplit[wave + 1]);

    const float4* s0q = reinterpret_cast<const float4*>(lds0);
    const float4* s1q = reinterpret_cast<const float4*>(lds1);
    float* outrow = out + (size_t)b * ROW;

    for (int s = sBeg; s < sEnd; ++s) {
        const int jb = __builtin_amdgcn_readfirstlane(sseg[s]);
        const int je = __builtin_amdgcn_readfirstlane(sseg[s + 1]);
        float4 acc0 = make_float4(0.f, 0.f, 0.f, 0.f);
        float4 acc1 = make_float4(0.f, 0.f, 0.f, 0.f);
        int j = jb;

        Meta mA, mB;
        if (j + 3 < je) {            // prologue: metas for first 4-path group
            mA = smeta[j + half];
            mB = smeta[j + 2 + half];
        }
        while (j + 7 < je) {
            // prefetch NEXT group's metas before current data reads
            const Meta nA = smeta[j + 4 + half];
            const Meta nB = smeta[j + 6 + half];
            const float4 uA = s0q[(mA.pp & 0xffffu) * (U / 4) + sub];
            const float4 wA = s1q[(mA.pp >> 16)     * (U / 4) + sub];
            const float4 uB = s0q[(mB.pp & 0xffffu) * (U / 4) + sub];
            const float4 wB = s1q[(mB.pp >> 16)     * (U / 4) + sub];
            acc0.x += mA.c * uA.x * wA.x;
            acc0.y += mA.c * uA.y * wA.y;
            acc0.z += mA.c * uA.z * wA.z;
            acc0.w += mA.c * uA.w * wA.w;
            acc1.x += mB.c * uB.x * wB.x;
            acc1.y += mB.c * uB.y * wB.y;
            acc1.z += mB.c * uB.z * wB.z;
            acc1.w += mB.c * uB.w * wB.w;
            mA = nA; mB = nB;
            j += 4;
        }
        if (j + 3 < je) {            // last full group (metas already resident)
            const float4 uA = s0q[(mA.pp & 0xffffu) * (U / 4) + sub];
            const float4 wA = s1q[(mA.pp >> 16)     * (U / 4) + sub];
            const float4 uB = s0q[(mB.pp & 0xffffu) * (U / 4) + sub];
            const float4 wB = s1q[(mB.pp >> 16)     * (U / 4) + sub];
            acc0.x += mA.c * uA.x * wA.x;
            acc0.y += mA.c * uA.y * wA.y;
            acc0.z += mA.c * uA.z * wA.z;
            acc0.w += mA.c * uA.w * wA.w;
            acc1.x += mB.c * uB.x * wB.x;
            acc1.y += mB.c * uB.y * wB.y;
            acc1.z += mB.c * uB.z * wB.z;
            acc1.w += mB.c * uB.w * wB.w;
            j += 4;
        }
        for (; j + 1 < je; j += 2) { // 2-path tail
            const Meta m = smeta[j + half];
            const float4 u = s0q[(m.pp & 0xffffu) * (U / 4) + sub];
            const float4 w = s1q[(m.pp >> 16)     * (U / 4) + sub];
            acc0.x += m.c * u.x * w.x;
            acc0.y += m.c * u.y * w.y;
            acc0.z += m.c * u.z * w.z;
            acc0.w += m.c * u.w * w.w;
        }
        if (j < je) {                // odd tail: upper half contributes 0
            const Meta m = smeta[j];
            const float cc = (half == 0) ? m.c : 0.f;
            const float4 u = s0q[(m.pp & 0xffffu) * (U / 4) + sub];
            const float4 w = s1q[(m.pp >> 16)     * (U / 4) + sub];
            acc0.x += cc * u.x * w.x;
            acc0.y += cc * u.y * w.y;
            acc0.z += cc * u.z * w.z;
            acc0.w += cc * u.w * w.w;
        }
        float4 a;
        a.x = acc0.x + acc1.x;
        a.y = acc0.y + acc1.y;
        a.z = acc0.z + acc1.z;
        a.w = acc0.w + acc1.w;
        a.x += __shfl_xor(a.x, 32, 64);
        a.y += __shfl_xor(a.y, 32, 64);
        a.z += __shfl_xor(a.z, 32, 64);
        a.w += __shfl_xor(a.w, 32, 64);
        if (half == 0)
            reinterpret_cast<float4*>(outrow + s * U)[sub] = a;
    }
}

extern "C" void kernel_launch(void* const* d_in, const int* in_sizes, int n_in,
                              void* d_out, int out_size, void* d_ws, size_t ws_size,
                              hipStream_t stream) {
    const float* x0     = (const float*)d_in[0];
    const float* x1     = (const float*)d_in[1];
    const float* coeffs = (const float*)d_in[2];
    const int*   p0     = (const int*)d_in[3];
    const int*   p1     = (const int*)d_in[4];
    const int*   pout   = (const int*)d_in[5];
    float* out = (float*)d_out;
    WS* ws = (WS*)d_ws;

    build_csr<<<1, 512, 0, stream>>>(coeffs, p0, p1, pout, ws);
    tp_kernel<<<2048, 512, 0, stream>>>(x0, x1, ws, out);
}